// Round 9
// baseline (410.623 us; speedup 1.0000x reference)
//
#include <hip/hip_runtime.h>

typedef unsigned short u16;
typedef short bfrag __attribute__((ext_vector_type(8)));   // 8 bf16 (4 VGPRs) for MFMA A/B
typedef float facc  __attribute__((ext_vector_type(4)));   // 4 fp32 accumulator

__device__ __forceinline__ float bf2f(u16 u) {
    union { unsigned int i; float f; } v; v.i = ((unsigned int)u) << 16; return v.f;
}
__device__ __forceinline__ u16 f2bf(float f) {
    union { float f; unsigned int i; } v; v.f = f;
    unsigned int r = v.i + 0x7FFFu + ((v.i >> 16) & 1u);
    return (u16)(r >> 16);
}

__device__ __forceinline__ void store_out(u16* p, float v)   { *p = f2bf(v); }
__device__ __forceinline__ void store_out(float* p, float v) { *p = v; }

// async global->LDS, 16B per lane; LDS dest = wave-uniform base + lane*16
__device__ __forceinline__ void gl2lds16(const u16* g, char* l) {
    __builtin_amdgcn_global_load_lds(
        (const __attribute__((address_space(1))) unsigned int*)g,
        (__attribute__((address_space(3))) unsigned int*)l,
        16, 0, 0);
}

// ---------------------------------------------------------------------------
// fp32 -> bf16 convert for the 4 weight tensors in one launch
// ---------------------------------------------------------------------------
__global__ void cvt4_k(const float* __restrict__ s0, u16* __restrict__ d0,
                       const float* __restrict__ s1, u16* __restrict__ d1,
                       const float* __restrict__ s2, u16* __restrict__ d2,
                       const float* __restrict__ s3, u16* __restrict__ d3) {
    int i = blockIdx.x * blockDim.x + threadIdx.x;
    if (i < 262144)        d0[i] = f2bf(s0[i]);
    else if (i < 1310720)  d1[i - 262144] = f2bf(s1[i - 262144]);
    else if (i < 2359296)  d2[i - 1310720] = f2bf(s2[i - 1310720]);
    else                   d3[i - 2359296] = f2bf(s3[i - 2359296]);
}

// ---------------------------------------------------------------------------
// Input transpose + fp32->bf16: xa/xb (b,256,4096) -> XT (16b, 4096, 256)
// ---------------------------------------------------------------------------
__global__ void transpose_in_k(const float* __restrict__ srcA,
                               const float* __restrict__ srcB,
                               u16* __restrict__ dst) {
    __shared__ u16 tile[64][65];
    const long SX = 1048576;  // 256*4096
    const int z  = blockIdx.z;
    const int c0 = blockIdx.x * 64;   // spatial
    const int r0 = blockIdx.y * 64;   // channel
    const int x  = threadIdx.x;
    const int y0 = threadIdx.y;
    const float* s = (z < 8 ? srcA : srcB) + (size_t)(z & 7) * SX;
    for (int i = 0; i < 8; ++i) {
        int r = y0 + i * 8;
        tile[r][x] = f2bf(s[(size_t)(r0 + r) * 4096 + c0 + x]);
    }
    __syncthreads();
    u16* d = dst + (size_t)z * SX;
    for (int i = 0; i < 8; ++i) {
        int c = y0 + i * 8;
        d[(size_t)(c0 + c) * 256 + r0 + x] = tile[x][c];
    }
}

// ---------------------------------------------------------------------------
// 128x128 NT GEMM (m97-class structure), kept for MODE 1 (conv2, small grid).
// ---------------------------------------------------------------------------
template <typename OutT, int MODE, bool PAIRED>
__global__ __launch_bounds__(256)
void gemm_nt(const u16* __restrict__ A0, const u16* __restrict__ A1, long strideA,
             const u16* __restrict__ B0, const u16* __restrict__ B1, long strideBT,
             OutT* __restrict__ C, long strideC, u16* __restrict__ CT,
             const float* __restrict__ bias, int M, int N, int K) {
    __shared__ __align__(16) char smem[32768];
    char* As = smem;
    char* Bs = smem + 16384;

    const int gx = gridDim.x, gy = gridDim.y;
    long id = blockIdx.x + (long)gx * (blockIdx.y + (long)gy * blockIdx.z);
    long total = (long)gx * gy * gridDim.z;
    long nid = (id & 7) * (total >> 3) + (id >> 3);
    const int bx = (int)(nid % gx);
    long rr = nid / gx;
    const int by = (int)(rr % gy);
    const int b  = (int)(rr / gy);

    const int m0 = bx * 128;
    const int n0 = by * 128;

    const u16* Ab; const u16* Bb;
    if (PAIRED) {
        const int bl = b & 7;
        Ab = (b < 8 ? A0 : A1) + (size_t)bl * strideA;
        Bb = (b < 8 ? B0 : B1) + (size_t)bl * strideBT;
    } else {
        Ab = A0 + (size_t)b * strideA;
        Bb = B0 + (size_t)b * strideBT;
    }

    const int t    = threadIdx.x;
    const int lane = t & 63;
    const int w    = t >> 6;
    const int wm   = (w & 1) * 64;
    const int wn   = (w >> 1) * 64;
    const int q    = lane >> 4;
    const int ln   = lane & 15;

    const int s0 = w * 64 + lane;
    const int s1 = s0 + 256;
    const int r0s = s0 >> 2, c0s = (s0 & 3) * 8;
    const int r1s = s1 >> 2, c1s = (s1 & 3) * 8;

    const u16* pA0 = Ab + (size_t)(m0 + r0s) * K + c0s;
    const u16* pA1 = Ab + (size_t)(m0 + r1s) * K + c1s;
    const u16* pB0 = Bb + (size_t)(n0 + r0s) * K + c0s;
    const u16* pB1 = Bb + (size_t)(n0 + r1s) * K + c1s;

    facc acc[4][4];
    for (int i = 0; i < 4; ++i)
        for (int j = 0; j < 4; ++j)
            acc[i][j] = (facc)0.0f;

    const int nK = K >> 6;
    for (int kt = 0; kt < nK; ++kt) {
        const int k0 = kt << 6;
        gl2lds16(pA0 + k0,      As + s0 * 16);
        gl2lds16(pA1 + k0,      As + s1 * 16);
        gl2lds16(pA0 + k0 + 32, As + 8192 + s0 * 16);
        gl2lds16(pA1 + k0 + 32, As + 8192 + s1 * 16);
        gl2lds16(pB0 + k0,      Bs + s0 * 16);
        gl2lds16(pB1 + k0,      Bs + s1 * 16);
        gl2lds16(pB0 + k0 + 32, Bs + 8192 + s0 * 16);
        gl2lds16(pB1 + k0 + 32, Bs + 8192 + s1 * 16);
        __syncthreads();
        for (int j = 0; j < 2; ++j) {
            const char* Aj = As + j * 8192;
            const char* Bj = Bs + j * 8192;
            bfrag af[4], bfr[4];
            for (int mt = 0; mt < 4; ++mt)
                af[mt] = *reinterpret_cast<const bfrag*>(Aj + (wm + mt * 16 + ln) * 64 + q * 16);
            for (int nt = 0; nt < 4; ++nt)
                bfr[nt] = *reinterpret_cast<const bfrag*>(Bj + (wn + nt * 16 + ln) * 64 + q * 16);
            for (int mt = 0; mt < 4; ++mt)
                for (int nt = 0; nt < 4; ++nt)
                    acc[mt][nt] = __builtin_amdgcn_mfma_f32_16x16x32_bf16(af[mt], bfr[nt], acc[mt][nt], 0, 0, 0);
        }
        __syncthreads();
    }

    if (MODE == 0) {
        u16* Cb = (u16*)C + (size_t)b * strideC;
        u16* dump = (u16*)smem;
        for (int mt = 0; mt < 4; ++mt)
            for (int nt = 0; nt < 4; ++nt)
                for (int r = 0; r < 4; ++r)
                    dump[(wm + mt * 16 + q * 4 + r) * 128 + wn + nt * 16 + ln] = f2bf(acc[mt][nt][r]);
        __syncthreads();
        for (int i = 0; i < 8; ++i) {
            const int row = w * 32 + i * 4 + (lane >> 4);
            const uint4 v = *reinterpret_cast<const uint4*>(dump + row * 128 + (lane & 15) * 8);
            *reinterpret_cast<uint4*>(Cb + (size_t)(m0 + row) * N + n0 + (lane & 15) * 8) = v;
        }
    } else {
        OutT* Cb = C + (size_t)b * strideC;
        for (int mt = 0; mt < 4; ++mt) {
            const int rbase = m0 + wm + mt * 16 + q * 4;
            for (int nt = 0; nt < 4; ++nt) {
                const int col = n0 + wn + nt * 16 + ln;
                for (int r = 0; r < 4; ++r)
                    store_out(&Cb[(size_t)(rbase + r) * N + col], acc[mt][nt][r] + bias[rbase + r]);
            }
        }
    }
}

// ---------------------------------------------------------------------------
// Shared macros for the latency-optimized BK=32 kernels
// ---------------------------------------------------------------------------
#define BARP() do { asm volatile("" ::: "memory"); __builtin_amdgcn_s_barrier(); asm volatile("" ::: "memory"); } while (0)
#define VM8P() asm volatile("s_waitcnt vmcnt(8)" ::: "memory")
#define VM4P() asm volatile("s_waitcnt vmcnt(4)" ::: "memory")
#define VM0P() asm volatile("s_waitcnt vmcnt(0)" ::: "memory")

#define STGP(KT, BUF) do { \
    gl2lds16(pA0 + (KT) * 32, smem + (BUF) * 16384 + s0 * 16); \
    gl2lds16(pA1 + (KT) * 32, smem + (BUF) * 16384 + s1 * 16); \
    gl2lds16(pB0 + (KT) * 32, smem + (BUF) * 16384 + 8192 + s0 * 16); \
    gl2lds16(pB1 + (KT) * 32, smem + (BUF) * 16384 + 8192 + s1 * 16); \
} while (0)

// ---------------------------------------------------------------------------
// Pool conv1 GEMM (verified round-8): 128x128 tile, BK=32, double-buffered
// 2-phase counted-vmcnt loop in 32 KiB LDS. See round-7 notes.
// ---------------------------------------------------------------------------
__global__ __launch_bounds__(256)
void gemm2p_pool(const u16* __restrict__ A, const u16* __restrict__ B0, long strideBT,
                 u16* __restrict__ C, long strideC, u16* __restrict__ CT,
                 const float* __restrict__ bias, int K) {
    __shared__ __align__(16) char smem[32768];

    const int gx = gridDim.x, gy = gridDim.y;
    long id = blockIdx.x + (long)gx * (blockIdx.y + (long)gy * blockIdx.z);
    long total = (long)gx * gy * gridDim.z;
    long nid = (id & 7) * (total >> 3) + (id >> 3);
    const int bx = (int)(nid % gx);
    long rr = nid / gx;
    const int by = (int)(rr % gy);
    const int b  = (int)(rr / gy);
    const int m0 = bx * 128;

    const u16* Bb = B0 + (size_t)b * strideBT;

    const int t    = threadIdx.x;
    const int lane = t & 63;
    const int w    = t >> 6;
    const int wm   = (w & 1) * 64;
    const int wn   = (w >> 1) * 64;
    const int q    = lane >> 4;
    const int ln   = lane & 15;

    const int s0 = w * 64 + lane;          // [0,256)
    const int s1 = s0 + 256;               // [256,512)
    const int r0s = s0 >> 2, c0s = s0 & 3;
    const int r1s = s1 >> 2, c1s = s1 & 3;
    const int x0 = (r0s >> 1) & 3, x1 = (r1s >> 1) & 3;
    const int gr0 = (2 * by + ((r0s >> 1) & 1)) * 64 + (r0s >> 2) * 2 + (r0s & 1);
    const int gr1 = (2 * by + ((r1s >> 1) & 1)) * 64 + (r1s >> 2) * 2 + (r1s & 1);

    const u16* pA0 = A  + (size_t)(m0 + r0s) * K + (c0s ^ x0) * 8;
    const u16* pA1 = A  + (size_t)(m0 + r1s) * K + (c1s ^ x1) * 8;
    const u16* pB0 = Bb + (size_t)gr0 * K + (c0s ^ x0) * 8;
    const u16* pB1 = Bb + (size_t)gr1 * K + (c1s ^ x1) * 8;

    facc acc[4][4];
    #pragma unroll
    for (int i = 0; i < 4; ++i)
        #pragma unroll
        for (int j = 0; j < 4; ++j)
            acc[i][j] = (facc)0.0f;

    const int nK = K >> 5;

    STGP(0, 0);
    for (int kt = 0; kt < nK; ++kt) {
        const bool more = (kt + 1 < nK);
        if (more) { STGP(kt + 1, (kt + 1) & 1); VM4P(); } else { VM0P(); }
        BARP();
        const char* Aj = smem + (kt & 1) * 16384;
        const char* Bj = Aj + 8192;
        bfrag af[4], bfr[4];
        #pragma unroll
        for (int mt = 0; mt < 4; ++mt) {
            const int row = wm + mt * 16 + ln;
            af[mt] = *reinterpret_cast<const bfrag*>(Aj + row * 64 + ((q ^ ((row >> 1) & 3)) << 4));
        }
        #pragma unroll
        for (int nt = 0; nt < 4; ++nt) {
            const int row = wn + nt * 16 + ln;
            bfr[nt] = *reinterpret_cast<const bfrag*>(Bj + row * 64 + ((q ^ ((row >> 1) & 3)) << 4));
        }
        #pragma unroll
        for (int mt = 0; mt < 4; ++mt)
            #pragma unroll
            for (int nt = 0; nt < 4; ++nt)
                acc[mt][nt] = __builtin_amdgcn_mfma_f32_16x16x32_bf16(af[mt], bfr[nt], acc[mt][nt], 0, 0, 0);
        BARP();
    }

    // in-register 2x2 maxpool epilogue (verified)
    u16* Cp  = C  + (size_t)b * strideC;    // FA  [ch][1024]
    u16* CTb = CT + (size_t)b * strideC;    // FAT [sp][1024]
    const int a = ln >> 2;
    #pragma unroll
    for (int mt = 0; mt < 4; ++mt) {
        const int chb = wm + mt * 16 + q * 4;
        float bs0 = bias[m0 + chb + 0];
        float bs1 = bias[m0 + chb + 1];
        float bs2 = bias[m0 + chb + 2];
        float bs3 = bias[m0 + chb + 3];
        #pragma unroll
        for (int nt = 0; nt < 4; ++nt) {
            const int xp = (wn >> 2) + nt * 4 + a;
            float p0 = acc[mt][nt][0] + bs0;
            float p1 = acc[mt][nt][1] + bs1;
            float p2 = acc[mt][nt][2] + bs2;
            float p3 = acc[mt][nt][3] + bs3;
            p0 = fmaxf(p0, __shfl_xor(p0, 1, 64)); p0 = fmaxf(p0, __shfl_xor(p0, 2, 64));
            p1 = fmaxf(p1, __shfl_xor(p1, 1, 64)); p1 = fmaxf(p1, __shfl_xor(p1, 2, 64));
            p2 = fmaxf(p2, __shfl_xor(p2, 1, 64)); p2 = fmaxf(p2, __shfl_xor(p2, 2, 64));
            p3 = fmaxf(p3, __shfl_xor(p3, 1, 64)); p3 = fmaxf(p3, __shfl_xor(p3, 2, 64));
            float s01 = (ln & 1) ? p1 : p0;
            float s23 = (ln & 1) ? p3 : p2;
            float sel = (ln & 2) ? s23 : s01;
            Cp[(size_t)(m0 + chb + (ln & 3)) * 1024 + by * 32 + xp] = f2bf(sel);
            if ((ln & 3) == 0) {
                uint2 pk;
                pk.x = (unsigned)f2bf(p0) | ((unsigned)f2bf(p1) << 16);
                pk.y = (unsigned)f2bf(p2) | ((unsigned)f2bf(p3) << 16);
                *reinterpret_cast<uint2*>(&CTb[(size_t)(by * 32 + xp) * 1024 + m0 + chb]) = pk;
            }
        }
    }
}

// ---------------------------------------------------------------------------
// Latency-optimized NT GEMM for 1024^3x16 (steps 4/5/8): 128x128 tile, BK=32,
// TRIPLE-buffered counted-vmcnt loop in 48 KiB LDS -> 3 blocks/CU.
//   Prefetch depth 2: iter kt stages tile kt+2 -> buf (kt+2)%3; vmcnt(8)
//   leaves tiles kt+1, kt+2 in flight (tail: vmcnt(4) then vmcnt(0)).
//   Ledger: steady-state 12 outstanding loads/wave; VM8 drains exactly
//   tile kt's 4. Buffer kt+2 overwrites tile kt-1, whose reads ended one
//   full barrier earlier (safe).
//   Chunk-XOR swizzle (verified round-7/8): physical 16B-chunk p of row r
//   holds logical chunk p ^ ((r>>1)&3); pre-swizzled global source + same
//   XOR on ds_read addresses. bf16 plain-C epilogue = verified LDS-dump.
// ---------------------------------------------------------------------------
template <bool PAIRED>
__global__ __launch_bounds__(256)
void gemm3b_nt(const u16* __restrict__ A0, const u16* __restrict__ A1, long strideA,
               const u16* __restrict__ B0, const u16* __restrict__ B1, long strideBT,
               u16* __restrict__ C, long strideC, int N, int K) {
    __shared__ __align__(16) char smem[49152];

    const int gx = gridDim.x, gy = gridDim.y;
    long id = blockIdx.x + (long)gx * (blockIdx.y + (long)gy * blockIdx.z);
    long total = (long)gx * gy * gridDim.z;
    long nid = (id & 7) * (total >> 3) + (id >> 3);
    const int bx = (int)(nid % gx);
    long rr = nid / gx;
    const int by = (int)(rr % gy);
    const int b  = (int)(rr / gy);
    const int m0 = bx * 128, n0 = by * 128;

    const u16* Ab; const u16* Bb;
    if (PAIRED) {
        const int bl = b & 7;
        Ab = (b < 8 ? A0 : A1) + (size_t)bl * strideA;
        Bb = (b < 8 ? B0 : B1) + (size_t)bl * strideBT;
    } else {
        Ab = A0 + (size_t)b * strideA;
        Bb = B0 + (size_t)b * strideBT;
    }

    const int t    = threadIdx.x;
    const int lane = t & 63;
    const int w    = t >> 6;
    const int wm   = (w & 1) * 64;
    const int wn   = (w >> 1) * 64;
    const int q    = lane >> 4;
    const int ln   = lane & 15;

    const int s0 = w * 64 + lane;
    const int s1 = s0 + 256;
    const int r0s = s0 >> 2, c0s = s0 & 3;
    const int r1s = s1 >> 2, c1s = s1 & 3;
    const int x0 = (r0s >> 1) & 3, x1 = (r1s >> 1) & 3;

    const u16* pA0 = Ab + (size_t)(m0 + r0s) * K + (c0s ^ x0) * 8;
    const u16* pA1 = Ab + (size_t)(m0 + r1s) * K + (c1s ^ x1) * 8;
    const u16* pB0 = Bb + (size_t)(n0 + r0s) * K + (c0s ^ x0) * 8;
    const u16* pB1 = Bb + (size_t)(n0 + r1s) * K + (c1s ^ x1) * 8;

    facc acc[4][4];
    #pragma unroll
    for (int i = 0; i < 4; ++i)
        #pragma unroll
        for (int j = 0; j < 4; ++j)
            acc[i][j] = (facc)0.0f;

    const int nK = K >> 5;     // K=1024 -> 32 iterations

    STGP(0, 0);
    STGP(1, 1);
    int cb = 0;                // compute-buffer index = kt % 3
    for (int kt = 0; kt < nK; ++kt) {
        const int rem = nK - 1 - kt;
        if (rem >= 2) {
            int sb = cb + 2; if (sb >= 3) sb -= 3;
            STGP(kt + 2, sb);
            VM8P();
        } else if (rem == 1) {
            VM4P();
        } else {
            VM0P();
        }
        BARP();
        const char* Aj = smem + cb * 16384;
        const char* Bj = Aj + 8192;
        bfrag af[4], bfr[4];
        #pragma unroll
        for (int mt = 0; mt < 4; ++mt) {
            const int row = wm + mt * 16 + ln;
            af[mt] = *reinterpret_cast<const bfrag*>(Aj + row * 64 + ((q ^ ((row >> 1) & 3)) << 4));
        }
        #pragma unroll
        for (int nt = 0; nt < 4; ++nt) {
            const int row = wn + nt * 16 + ln;
            bfr[nt] = *reinterpret_cast<const bfrag*>(Bj + row * 64 + ((q ^ ((row >> 1) & 3)) << 4));
        }
        #pragma unroll
        for (int mt = 0; mt < 4; ++mt)
            #pragma unroll
            for (int nt = 0; nt < 4; ++nt)
                acc[mt][nt] = __builtin_amdgcn_mfma_f32_16x16x32_bf16(af[mt], bfr[nt], acc[mt][nt], 0, 0, 0);
        BARP();
        ++cb; if (cb == 3) cb = 0;
    }

    // verified LDS-dump bf16 epilogue (all LDS reads done past final barrier)
    u16* Cb = C + (size_t)b * strideC;
    u16* dump = (u16*)smem;
    #pragma unroll
    for (int mt = 0; mt < 4; ++mt)
        #pragma unroll
        for (int nt = 0; nt < 4; ++nt)
            #pragma unroll
            for (int r = 0; r < 4; ++r)
                dump[(wm + mt * 16 + q * 4 + r) * 128 + wn + nt * 16 + ln] = f2bf(acc[mt][nt][r]);
    __syncthreads();
    #pragma unroll
    for (int i = 0; i < 8; ++i) {
        const int row = w * 32 + i * 4 + (lane >> 4);
        const uint4 v = *reinterpret_cast<const uint4*>(dump + row * 128 + (lane & 15) * 8);
        *reinterpret_cast<uint4*>(Cb + (size_t)(m0 + row) * N + n0 + (lane & 15) * 8) = v;
    }
}

// ---------------------------------------------------------------------------
// Row inverse-L2-norm of relu(fm): rinv[row] = 1/sqrt(sum relu(v)^2 + eps)
// ---------------------------------------------------------------------------
__global__ void norm_rk(const u16* __restrict__ fm, float* __restrict__ rinv) {
    __shared__ float red[4];
    const long row = blockIdx.x;
    const u16* p = fm + row * 1024;
    const int t = threadIdx.x;
    uint2 raw = *reinterpret_cast<const uint2*>(p + t * 4);
    float v0 = fmaxf(bf2f((u16)(raw.x & 0xFFFF)), 0.f);
    float v1 = fmaxf(bf2f((u16)(raw.x >> 16)), 0.f);
    float v2 = fmaxf(bf2f((u16)(raw.y & 0xFFFF)), 0.f);
    float v3 = fmaxf(bf2f((u16)(raw.y >> 16)), 0.f);
    float s = v0 * v0 + v1 * v1 + v2 * v2 + v3 * v3;
    for (int off = 32; off; off >>= 1) s += __shfl_down(s, off, 64);
    if ((t & 63) == 0) red[t >> 6] = s;
    __syncthreads();
    if (t == 0)
        rinv[row] = 1.0f / sqrtf(red[0] + red[1] + red[2] + red[3] + 1e-6f);
}

// ---------------------------------------------------------------------------
// Fused relu+scale+transpose: dst[q][p] = relu(src[p][q]) * rinv[p], per batch.
// ---------------------------------------------------------------------------
__global__ void transpose_scale_k(const u16* __restrict__ src,
                                  const float* __restrict__ rinv,
                                  u16* __restrict__ dst) {
    __shared__ u16 tile[64][65];
    const long S = 1048576;
    const int b  = blockIdx.z;
    const int c0 = blockIdx.x * 64;   // q
    const int r0 = blockIdx.y * 64;   // p
    const int x  = threadIdx.x;
    const int y0 = threadIdx.y;
    const u16* s = src + (size_t)b * S;
    const float* rv = rinv + (size_t)b * 1024;
    for (int i = 0; i < 8; ++i) {
        int r = y0 + i * 8;
        float v = fmaxf(bf2f(s[(size_t)(r0 + r) * 1024 + c0 + x]), 0.f) * rv[r0 + r];
        tile[r][x] = f2bf(v);
    }
    __syncthreads();
    u16* d = dst + (size_t)b * S;
    for (int i = 0; i < 8; ++i) {
        int c = y0 + i * 8;
        d[(size_t)(c0 + c) * 1024 + r0 + x] = tile[x][c];
    }
}

// ---------------------------------------------------------------------------
// Bilinear x2 upsample (align_corners): V fp32 (4096 ch-imgs, 32,32) -> out fp32
// ---------------------------------------------------------------------------
__global__ void upsample_k(const float* __restrict__ V, float* __restrict__ out, int total) {
    int idx = blockIdx.x * blockDim.x + threadIdx.x;
    if (idx >= total) return;
    int X  = idx & 63;
    int Y  = (idx >> 6) & 63;
    long bo = idx >> 12;
    const float* p = V + bo * 1024;
    const float sc = 31.0f / 63.0f;
    float ys = Y * sc;
    float xs = X * sc;
    int y0 = (int)ys; int x0 = (int)xs;
    int y1 = y0 + 1; if (y1 > 31) y1 = 31;
    int x1 = x0 + 1; if (x1 > 31) x1 = 31;
    float ty = ys - y0, tx = xs - x0;
    float v00 = p[y0 * 32 + x0], v01 = p[y0 * 32 + x1];
    float v10 = p[y1 * 32 + x0], v11 = p[y1 * 32 + x1];
    out[idx] = (1.f - ty) * ((1.f - tx) * v00 + tx * v01) + ty * ((1.f - tx) * v10 + tx * v11);
}

// ---------------------------------------------------------------------------
extern "C" void kernel_launch(void* const* d_in, const int* in_sizes, int n_in,
                              void* d_out, int out_size, void* d_ws, size_t ws_size,
                              hipStream_t stream) {
    const float* xa      = (const float*)d_in[0];   // (8,256,64,64)
    const float* xb      = (const float*)d_in[1];
    const float* conv_w  = (const float*)d_in[2];   // (1024,256)
    const float* conv_b  = (const float*)d_in[3];   // (1024,)
    const float* We      = (const float*)d_in[4];   // (1024,1024)
    const float* We2     = (const float*)d_in[5];   // (1024,1024)
    const float* conv2_w = (const float*)d_in[6];   // (256,1024)
    const float* conv2_b = (const float*)d_in[7];   // (256,)
    float* out = (float*)d_out;
    char* ws = (char*)d_ws;

    const long S1M = 1048576;
    const long MiB = 1048576;

    u16*   XT  = (u16*)(ws + 0);
    u16*   T1  = (u16*)(ws + 0);
    u16*   MT  = (u16*)(ws + 0);
    u16*   FA  = (u16*)(ws + 32 * MiB);
    u16*   FB  = (u16*)(ws + 48 * MiB);
    u16*   FAT = (u16*)(ws + 64 * MiB);
    u16*   FBT = (u16*)(ws + 80 * MiB);
    float* V   = (float*)(ws + 64 * MiB);
    u16*   FM  = (u16*)(ws + 96 * MiB);
    u16*   Z   = (u16*)(ws + 96 * MiB);
    u16*   CW  = (u16*)(ws + 128 * MiB);
    u16*   WE  = (u16*)(ws + 128 * MiB + 524288);
    u16*   WE2 = (u16*)(ws + 128 * MiB + 2621440);
    u16*   C2W = (u16*)(ws + 128 * MiB + 4718592);
    float* RIV = (float*)(ws + 128 * MiB + 5242880);   // 16x1024 fp32

    const dim3 tb64(64, 8);

    // 1. weights fp32 -> bf16
    cvt4_k<<<10240, 256, 0, stream>>>(conv_w, CW, We, WE, We2, WE2, conv2_w, C2W);

    // 2. input transpose+convert: XT[z][spatial][ch]
    transpose_in_k<<<dim3(64, 4, 16), tb64, 0, stream>>>(xa, xb, XT);

    // 3. conv1 + bias + 2x2 maxpool -> FA/FB (ch-major) + FAT/FBT (spatial-major)
    gemm2p_pool<<<dim3(8, 32, 16), 256, 0, stream>>>(
        CW, XT, S1M, FA, S1M, FAT, conv_b, 256);

    // 4. T1: path a = FBT . We^T ; path b = FAT . We2^T   (3-buffer BK=32)
    gemm3b_nt<true><<<dim3(8, 8, 16), 256, 0, stream>>>(
        FBT, FAT, S1M, WE, WE2, 0, T1, S1M, 1024, 1024);

    // 5. fm: path a = T1 . FAT^T ; path b = T1 . FBT^T
    gemm3b_nt<true><<<dim3(8, 8, 16), 256, 0, stream>>>(
        T1, T1 + 8 * S1M, S1M, FAT, FBT, S1M, FM, S1M, 1024, 1024);

    // 6. row inverse norms of relu(fm)
    norm_rk<<<16384, 256, 0, stream>>>(FM, RIV);

    // 7. MT[q][p] = relu(fm[p][q]) * rinv[p]
    transpose_scale_k<<<dim3(16, 16, 16), tb64, 0, stream>>>(FM, RIV, MT);

    // 8. en: path a = FA . MT^T ; path b = FB . MT^T  -> Z (ch x spatial)
    gemm3b_nt<true><<<dim3(8, 8, 16), 256, 0, stream>>>(
        FA, FB, S1M, MT, MT + 8 * S1M, S1M, Z, S1M, 1024, 1024);

    // 9. conv2 + bias (fp32 out)
    gemm_nt<float, 1, false><<<dim3(2, 8, 16), 256, 0, stream>>>(
        C2W, C2W, 0, Z, Z, S1M, V, 256L * 1024, nullptr, conv2_b, 256, 1024, 1024);

    // 10. bilinear x2 upsample -> d_out
    upsample_k<<<65536, 256, 0, stream>>>(V, out, 16 * 256 * 4096);
}

// Round 10
// 395.426 us; speedup vs baseline: 1.0384x; 1.0384x over previous
//
#include <hip/hip_runtime.h>

typedef unsigned short u16;
typedef short bfrag __attribute__((ext_vector_type(8)));   // 8 bf16 (4 VGPRs) for MFMA A/B
typedef float facc  __attribute__((ext_vector_type(4)));   // 4 fp32 accumulator

__device__ __forceinline__ float bf2f(u16 u) {
    union { unsigned int i; float f; } v; v.i = ((unsigned int)u) << 16; return v.f;
}
__device__ __forceinline__ u16 f2bf(float f) {
    union { float f; unsigned int i; } v; v.f = f;
    unsigned int r = v.i + 0x7FFFu + ((v.i >> 16) & 1u);
    return (u16)(r >> 16);
}

// async global->LDS, 16B per lane; LDS dest = wave-uniform base + lane*16
__device__ __forceinline__ void gl2lds16(const u16* g, char* l) {
    __builtin_amdgcn_global_load_lds(
        (const __attribute__((address_space(1))) unsigned int*)g,
        (__attribute__((address_space(3))) unsigned int*)l,
        16, 0, 0);
}

// ---------------------------------------------------------------------------
// fp32 -> bf16 convert for the 4 weight tensors in one launch
// ---------------------------------------------------------------------------
__global__ void cvt4_k(const float* __restrict__ s0, u16* __restrict__ d0,
                       const float* __restrict__ s1, u16* __restrict__ d1,
                       const float* __restrict__ s2, u16* __restrict__ d2,
                       const float* __restrict__ s3, u16* __restrict__ d3) {
    int i = blockIdx.x * blockDim.x + threadIdx.x;
    if (i < 262144)        d0[i] = f2bf(s0[i]);
    else if (i < 1310720)  d1[i - 262144] = f2bf(s1[i - 262144]);
    else if (i < 2359296)  d2[i - 1310720] = f2bf(s2[i - 1310720]);
    else                   d3[i - 2359296] = f2bf(s3[i - 2359296]);
}

// ---------------------------------------------------------------------------
// Input transpose + fp32->bf16: xa/xb (b,256,4096) -> XT (16b, 4096, 256)
// ---------------------------------------------------------------------------
__global__ void transpose_in_k(const float* __restrict__ srcA,
                               const float* __restrict__ srcB,
                               u16* __restrict__ dst) {
    __shared__ u16 tile[64][65];
    const long SX = 1048576;  // 256*4096
    const int z  = blockIdx.z;
    const int c0 = blockIdx.x * 64;   // spatial
    const int r0 = blockIdx.y * 64;   // channel
    const int x  = threadIdx.x;
    const int y0 = threadIdx.y;
    const float* s = (z < 8 ? srcA : srcB) + (size_t)(z & 7) * SX;
    for (int i = 0; i < 8; ++i) {
        int r = y0 + i * 8;
        tile[r][x] = f2bf(s[(size_t)(r0 + r) * 4096 + c0 + x]);
    }
    __syncthreads();
    u16* d = dst + (size_t)z * SX;
    for (int i = 0; i < 8; ++i) {
        int c = y0 + i * 8;
        d[(size_t)(c0 + c) * 256 + r0 + x] = tile[x][c];
    }
}

// ---------------------------------------------------------------------------
// Shared macros for the latency-optimized BK=32 kernels
// ---------------------------------------------------------------------------
#define BARP() do { asm volatile("" ::: "memory"); __builtin_amdgcn_s_barrier(); asm volatile("" ::: "memory"); } while (0)
#define VM8P() asm volatile("s_waitcnt vmcnt(8)" ::: "memory")
#define VM4P() asm volatile("s_waitcnt vmcnt(4)" ::: "memory")
#define VM0P() asm volatile("s_waitcnt vmcnt(0)" ::: "memory")

#define STGP(KT, BUF) do { \
    gl2lds16(pA0 + (KT) * 32, smem + (BUF) * 16384 + s0 * 16); \
    gl2lds16(pA1 + (KT) * 32, smem + (BUF) * 16384 + s1 * 16); \
    gl2lds16(pB0 + (KT) * 32, smem + (BUF) * 16384 + 8192 + s0 * 16); \
    gl2lds16(pB1 + (KT) * 32, smem + (BUF) * 16384 + 8192 + s1 * 16); \
} while (0)

// ---------------------------------------------------------------------------
// Pool conv1 GEMM (verified round-8): 128x128 tile, BK=32, double-buffered
// 2-phase counted-vmcnt loop in 32 KiB LDS. See round-7 notes.
// ---------------------------------------------------------------------------
__global__ __launch_bounds__(256)
void gemm2p_pool(const u16* __restrict__ A, const u16* __restrict__ B0, long strideBT,
                 u16* __restrict__ C, long strideC, u16* __restrict__ CT,
                 const float* __restrict__ bias, int K) {
    __shared__ __align__(16) char smem[32768];

    const int gx = gridDim.x, gy = gridDim.y;
    long id = blockIdx.x + (long)gx * (blockIdx.y + (long)gy * blockIdx.z);
    long total = (long)gx * gy * gridDim.z;
    long nid = (id & 7) * (total >> 3) + (id >> 3);
    const int bx = (int)(nid % gx);
    long rr = nid / gx;
    const int by = (int)(rr % gy);
    const int b  = (int)(rr / gy);
    const int m0 = bx * 128;

    const u16* Bb = B0 + (size_t)b * strideBT;

    const int t    = threadIdx.x;
    const int lane = t & 63;
    const int w    = t >> 6;
    const int wm   = (w & 1) * 64;
    const int wn   = (w >> 1) * 64;
    const int q    = lane >> 4;
    const int ln   = lane & 15;

    const int s0 = w * 64 + lane;          // [0,256)
    const int s1 = s0 + 256;               // [256,512)
    const int r0s = s0 >> 2, c0s = s0 & 3;
    const int r1s = s1 >> 2, c1s = s1 & 3;
    const int x0 = (r0s >> 1) & 3, x1 = (r1s >> 1) & 3;
    const int gr0 = (2 * by + ((r0s >> 1) & 1)) * 64 + (r0s >> 2) * 2 + (r0s & 1);
    const int gr1 = (2 * by + ((r1s >> 1) & 1)) * 64 + (r1s >> 2) * 2 + (r1s & 1);

    const u16* pA0 = A  + (size_t)(m0 + r0s) * K + (c0s ^ x0) * 8;
    const u16* pA1 = A  + (size_t)(m0 + r1s) * K + (c1s ^ x1) * 8;
    const u16* pB0 = Bb + (size_t)gr0 * K + (c0s ^ x0) * 8;
    const u16* pB1 = Bb + (size_t)gr1 * K + (c1s ^ x1) * 8;

    facc acc[4][4];
    #pragma unroll
    for (int i = 0; i < 4; ++i)
        #pragma unroll
        for (int j = 0; j < 4; ++j)
            acc[i][j] = (facc)0.0f;

    const int nK = K >> 5;

    STGP(0, 0);
    for (int kt = 0; kt < nK; ++kt) {
        const bool more = (kt + 1 < nK);
        if (more) { STGP(kt + 1, (kt + 1) & 1); VM4P(); } else { VM0P(); }
        BARP();
        const char* Aj = smem + (kt & 1) * 16384;
        const char* Bj = Aj + 8192;
        bfrag af[4], bfr[4];
        #pragma unroll
        for (int mt = 0; mt < 4; ++mt) {
            const int row = wm + mt * 16 + ln;
            af[mt] = *reinterpret_cast<const bfrag*>(Aj + row * 64 + ((q ^ ((row >> 1) & 3)) << 4));
        }
        #pragma unroll
        for (int nt = 0; nt < 4; ++nt) {
            const int row = wn + nt * 16 + ln;
            bfr[nt] = *reinterpret_cast<const bfrag*>(Bj + row * 64 + ((q ^ ((row >> 1) & 3)) << 4));
        }
        #pragma unroll
        for (int mt = 0; mt < 4; ++mt)
            #pragma unroll
            for (int nt = 0; nt < 4; ++nt)
                acc[mt][nt] = __builtin_amdgcn_mfma_f32_16x16x32_bf16(af[mt], bfr[nt], acc[mt][nt], 0, 0, 0);
        BARP();
    }

    // in-register 2x2 maxpool epilogue (verified)
    u16* Cp  = C  + (size_t)b * strideC;    // FA  [ch][1024]
    u16* CTb = CT + (size_t)b * strideC;    // FAT [sp][1024]
    const int a = ln >> 2;
    #pragma unroll
    for (int mt = 0; mt < 4; ++mt) {
        const int chb = wm + mt * 16 + q * 4;
        float bs0 = bias[m0 + chb + 0];
        float bs1 = bias[m0 + chb + 1];
        float bs2 = bias[m0 + chb + 2];
        float bs3 = bias[m0 + chb + 3];
        #pragma unroll
        for (int nt = 0; nt < 4; ++nt) {
            const int xp = (wn >> 2) + nt * 4 + a;
            float p0 = acc[mt][nt][0] + bs0;
            float p1 = acc[mt][nt][1] + bs1;
            float p2 = acc[mt][nt][2] + bs2;
            float p3 = acc[mt][nt][3] + bs3;
            p0 = fmaxf(p0, __shfl_xor(p0, 1, 64)); p0 = fmaxf(p0, __shfl_xor(p0, 2, 64));
            p1 = fmaxf(p1, __shfl_xor(p1, 1, 64)); p1 = fmaxf(p1, __shfl_xor(p1, 2, 64));
            p2 = fmaxf(p2, __shfl_xor(p2, 1, 64)); p2 = fmaxf(p2, __shfl_xor(p2, 2, 64));
            p3 = fmaxf(p3, __shfl_xor(p3, 1, 64)); p3 = fmaxf(p3, __shfl_xor(p3, 2, 64));
            float s01 = (ln & 1) ? p1 : p0;
            float s23 = (ln & 1) ? p3 : p2;
            float sel = (ln & 2) ? s23 : s01;
            Cp[(size_t)(m0 + chb + (ln & 3)) * 1024 + by * 32 + xp] = f2bf(sel);
            if ((ln & 3) == 0) {
                uint2 pk;
                pk.x = (unsigned)f2bf(p0) | ((unsigned)f2bf(p1) << 16);
                pk.y = (unsigned)f2bf(p2) | ((unsigned)f2bf(p3) << 16);
                *reinterpret_cast<uint2*>(&CTb[(size_t)(by * 32 + xp) * 1024 + m0 + chb]) = pk;
            }
        }
    }
}

// ---------------------------------------------------------------------------
// Latency-optimized NT GEMM for 1024^3x16 (steps 4/5/8): 128x128 tile, BK=32,
// TRIPLE-buffered counted-vmcnt loop in 48 KiB LDS (verified round-9).
// Ledger: iter kt stages tile kt+2; VM8 leaves kt+1/kt+2 in flight (tail
// VM4 then VM0). Chunk-XOR swizzle both-sides. LDS-dump bf16 epilogue.
// ---------------------------------------------------------------------------
template <bool PAIRED>
__global__ __launch_bounds__(256)
void gemm3b_nt(const u16* __restrict__ A0, const u16* __restrict__ A1, long strideA,
               const u16* __restrict__ B0, const u16* __restrict__ B1, long strideBT,
               u16* __restrict__ C, long strideC, int N, int K) {
    __shared__ __align__(16) char smem[49152];

    const int gx = gridDim.x, gy = gridDim.y;
    long id = blockIdx.x + (long)gx * (blockIdx.y + (long)gy * blockIdx.z);
    long total = (long)gx * gy * gridDim.z;
    long nid = (id & 7) * (total >> 3) + (id >> 3);
    const int bx = (int)(nid % gx);
    long rr = nid / gx;
    const int by = (int)(rr % gy);
    const int b  = (int)(rr / gy);
    const int m0 = bx * 128, n0 = by * 128;

    const u16* Ab; const u16* Bb;
    if (PAIRED) {
        const int bl = b & 7;
        Ab = (b < 8 ? A0 : A1) + (size_t)bl * strideA;
        Bb = (b < 8 ? B0 : B1) + (size_t)bl * strideBT;
    } else {
        Ab = A0 + (size_t)b * strideA;
        Bb = B0 + (size_t)b * strideBT;
    }

    const int t    = threadIdx.x;
    const int lane = t & 63;
    const int w    = t >> 6;
    const int wm   = (w & 1) * 64;
    const int wn   = (w >> 1) * 64;
    const int q    = lane >> 4;
    const int ln   = lane & 15;

    const int s0 = w * 64 + lane;
    const int s1 = s0 + 256;
    const int r0s = s0 >> 2, c0s = s0 & 3;
    const int r1s = s1 >> 2, c1s = s1 & 3;
    const int x0 = (r0s >> 1) & 3, x1 = (r1s >> 1) & 3;

    const u16* pA0 = Ab + (size_t)(m0 + r0s) * K + (c0s ^ x0) * 8;
    const u16* pA1 = Ab + (size_t)(m0 + r1s) * K + (c1s ^ x1) * 8;
    const u16* pB0 = Bb + (size_t)(n0 + r0s) * K + (c0s ^ x0) * 8;
    const u16* pB1 = Bb + (size_t)(n0 + r1s) * K + (c1s ^ x1) * 8;

    facc acc[4][4];
    #pragma unroll
    for (int i = 0; i < 4; ++i)
        #pragma unroll
        for (int j = 0; j < 4; ++j)
            acc[i][j] = (facc)0.0f;

    const int nK = K >> 5;     // K=1024 -> 32 iterations

    STGP(0, 0);
    STGP(1, 1);
    int cb = 0;                // compute-buffer index = kt % 3
    for (int kt = 0; kt < nK; ++kt) {
        const int rem = nK - 1 - kt;
        if (rem >= 2) {
            int sb = cb + 2; if (sb >= 3) sb -= 3;
            STGP(kt + 2, sb);
            VM8P();
        } else if (rem == 1) {
            VM4P();
        } else {
            VM0P();
        }
        BARP();
        const char* Aj = smem + cb * 16384;
        const char* Bj = Aj + 8192;
        bfrag af[4], bfr[4];
        #pragma unroll
        for (int mt = 0; mt < 4; ++mt) {
            const int row = wm + mt * 16 + ln;
            af[mt] = *reinterpret_cast<const bfrag*>(Aj + row * 64 + ((q ^ ((row >> 1) & 3)) << 4));
        }
        #pragma unroll
        for (int nt = 0; nt < 4; ++nt) {
            const int row = wn + nt * 16 + ln;
            bfr[nt] = *reinterpret_cast<const bfrag*>(Bj + row * 64 + ((q ^ ((row >> 1) & 3)) << 4));
        }
        #pragma unroll
        for (int mt = 0; mt < 4; ++mt)
            #pragma unroll
            for (int nt = 0; nt < 4; ++nt)
                acc[mt][nt] = __builtin_amdgcn_mfma_f32_16x16x32_bf16(af[mt], bfr[nt], acc[mt][nt], 0, 0, 0);
        BARP();
        ++cb; if (cb == 3) cb = 0;
    }

    // verified LDS-dump bf16 epilogue
    u16* Cb = C + (size_t)b * strideC;
    u16* dump = (u16*)smem;
    #pragma unroll
    for (int mt = 0; mt < 4; ++mt)
        #pragma unroll
        for (int nt = 0; nt < 4; ++nt)
            #pragma unroll
            for (int r = 0; r < 4; ++r)
                dump[(wm + mt * 16 + q * 4 + r) * 128 + wn + nt * 16 + ln] = f2bf(acc[mt][nt][r]);
    __syncthreads();
    #pragma unroll
    for (int i = 0; i < 8; ++i) {
        const int row = w * 32 + i * 4 + (lane >> 4);
        const uint4 v = *reinterpret_cast<const uint4*>(dump + row * 128 + (lane & 15) * 8);
        *reinterpret_cast<uint4*>(Cb + (size_t)(m0 + row) * N + n0 + (lane & 15) * 8) = v;
    }
}

// ---------------------------------------------------------------------------
// conv2 GEMM (step 9): same verified triple-buffer BK=32 loop, fp32+bias
// epilogue (the previously-verified MODE-1 store pattern). A = weights
// (shared across batches), B = Z per batch. M=256 (grid.x=2), N=1024.
// ---------------------------------------------------------------------------
__global__ __launch_bounds__(256)
void gemm3b_c2(const u16* __restrict__ A, const u16* __restrict__ B0, long strideBT,
               float* __restrict__ C, long strideC,
               const float* __restrict__ bias, int N, int K) {
    __shared__ __align__(16) char smem[49152];

    const int gx = gridDim.x, gy = gridDim.y;
    long id = blockIdx.x + (long)gx * (blockIdx.y + (long)gy * blockIdx.z);
    long total = (long)gx * gy * gridDim.z;
    long nid = (id & 7) * (total >> 3) + (id >> 3);
    const int bx = (int)(nid % gx);
    long rr = nid / gx;
    const int by = (int)(rr % gy);
    const int b  = (int)(rr / gy);
    const int m0 = bx * 128, n0 = by * 128;

    const u16* Bb = B0 + (size_t)b * strideBT;

    const int t    = threadIdx.x;
    const int lane = t & 63;
    const int w    = t >> 6;
    const int wm   = (w & 1) * 64;
    const int wn   = (w >> 1) * 64;
    const int q    = lane >> 4;
    const int ln   = lane & 15;

    const int s0 = w * 64 + lane;
    const int s1 = s0 + 256;
    const int r0s = s0 >> 2, c0s = s0 & 3;
    const int r1s = s1 >> 2, c1s = s1 & 3;
    const int x0 = (r0s >> 1) & 3, x1 = (r1s >> 1) & 3;

    const u16* pA0 = A  + (size_t)(m0 + r0s) * K + (c0s ^ x0) * 8;
    const u16* pA1 = A  + (size_t)(m0 + r1s) * K + (c1s ^ x1) * 8;
    const u16* pB0 = Bb + (size_t)(n0 + r0s) * K + (c0s ^ x0) * 8;
    const u16* pB1 = Bb + (size_t)(n0 + r1s) * K + (c1s ^ x1) * 8;

    facc acc[4][4];
    #pragma unroll
    for (int i = 0; i < 4; ++i)
        #pragma unroll
        for (int j = 0; j < 4; ++j)
            acc[i][j] = (facc)0.0f;

    const int nK = K >> 5;

    STGP(0, 0);
    STGP(1, 1);
    int cb = 0;
    for (int kt = 0; kt < nK; ++kt) {
        const int rem = nK - 1 - kt;
        if (rem >= 2) {
            int sb = cb + 2; if (sb >= 3) sb -= 3;
            STGP(kt + 2, sb);
            VM8P();
        } else if (rem == 1) {
            VM4P();
        } else {
            VM0P();
        }
        BARP();
        const char* Aj = smem + cb * 16384;
        const char* Bj = Aj + 8192;
        bfrag af[4], bfr[4];
        #pragma unroll
        for (int mt = 0; mt < 4; ++mt) {
            const int row = wm + mt * 16 + ln;
            af[mt] = *reinterpret_cast<const bfrag*>(Aj + row * 64 + ((q ^ ((row >> 1) & 3)) << 4));
        }
        #pragma unroll
        for (int nt = 0; nt < 4; ++nt) {
            const int row = wn + nt * 16 + ln;
            bfr[nt] = *reinterpret_cast<const bfrag*>(Bj + row * 64 + ((q ^ ((row >> 1) & 3)) << 4));
        }
        #pragma unroll
        for (int mt = 0; mt < 4; ++mt)
            #pragma unroll
            for (int nt = 0; nt < 4; ++nt)
                acc[mt][nt] = __builtin_amdgcn_mfma_f32_16x16x32_bf16(af[mt], bfr[nt], acc[mt][nt], 0, 0, 0);
        BARP();
        ++cb; if (cb == 3) cb = 0;
    }

    // verified MODE-1 epilogue: +bias, fp32 out
    float* Cb = C + (size_t)b * strideC;
    #pragma unroll
    for (int mt = 0; mt < 4; ++mt) {
        const int rbase = m0 + wm + mt * 16 + q * 4;
        #pragma unroll
        for (int nt = 0; nt < 4; ++nt) {
            const int col = n0 + wn + nt * 16 + ln;
            #pragma unroll
            for (int r = 0; r < 4; ++r)
                Cb[(size_t)(rbase + r) * N + col] = acc[mt][nt][r] + bias[rbase + r];
        }
    }
}

// ---------------------------------------------------------------------------
// Row inverse-L2-norm of relu(fm): rinv[row] = 1/sqrt(sum relu(v)^2 + eps)
// ---------------------------------------------------------------------------
__global__ void norm_rk(const u16* __restrict__ fm, float* __restrict__ rinv) {
    __shared__ float red[4];
    const long row = blockIdx.x;
    const u16* p = fm + row * 1024;
    const int t = threadIdx.x;
    uint2 raw = *reinterpret_cast<const uint2*>(p + t * 4);
    float v0 = fmaxf(bf2f((u16)(raw.x & 0xFFFF)), 0.f);
    float v1 = fmaxf(bf2f((u16)(raw.x >> 16)), 0.f);
    float v2 = fmaxf(bf2f((u16)(raw.y & 0xFFFF)), 0.f);
    float v3 = fmaxf(bf2f((u16)(raw.y >> 16)), 0.f);
    float s = v0 * v0 + v1 * v1 + v2 * v2 + v3 * v3;
    for (int off = 32; off; off >>= 1) s += __shfl_down(s, off, 64);
    if ((t & 63) == 0) red[t >> 6] = s;
    __syncthreads();
    if (t == 0)
        rinv[row] = 1.0f / sqrtf(red[0] + red[1] + red[2] + red[3] + 1e-6f);
}

// ---------------------------------------------------------------------------
// Fused relu+scale+transpose: dst[q][p] = relu(src[p][q]) * rinv[p], per batch.
// ---------------------------------------------------------------------------
__global__ void transpose_scale_k(const u16* __restrict__ src,
                                  const float* __restrict__ rinv,
                                  u16* __restrict__ dst) {
    __shared__ u16 tile[64][65];
    const long S = 1048576;
    const int b  = blockIdx.z;
    const int c0 = blockIdx.x * 64;   // q
    const int r0 = blockIdx.y * 64;   // p
    const int x  = threadIdx.x;
    const int y0 = threadIdx.y;
    const u16* s = src + (size_t)b * S;
    const float* rv = rinv + (size_t)b * 1024;
    for (int i = 0; i < 8; ++i) {
        int r = y0 + i * 8;
        float v = fmaxf(bf2f(s[(size_t)(r0 + r) * 1024 + c0 + x]), 0.f) * rv[r0 + r];
        tile[r][x] = f2bf(v);
    }
    __syncthreads();
    u16* d = dst + (size_t)b * S;
    for (int i = 0; i < 8; ++i) {
        int c = y0 + i * 8;
        d[(size_t)(c0 + c) * 1024 + r0 + x] = tile[x][c];
    }
}

// ---------------------------------------------------------------------------
// Bilinear x2 upsample (align_corners), float4 stores: each thread computes
// 4 consecutive X outputs (shared y0/y1/ty), writes 16B.
// ---------------------------------------------------------------------------
__global__ void upsample4_k(const float* __restrict__ V, float* __restrict__ out, int total4) {
    int idx = blockIdx.x * blockDim.x + threadIdx.x;
    if (idx >= total4) return;
    int x4 = idx & 15;          // X group of 4
    int Y  = (idx >> 4) & 63;
    long bo = idx >> 10;
    const float* p = V + bo * 1024;
    const float sc = 31.0f / 63.0f;
    float ys = Y * sc;
    int y0 = (int)ys; int y1 = y0 + 1; if (y1 > 31) y1 = 31;
    float ty = ys - y0;
    const float* r0 = p + y0 * 32;
    const float* r1 = p + y1 * 32;
    float4 o;
    float* op = (float*)&o;
    #pragma unroll
    for (int j = 0; j < 4; ++j) {
        int X = x4 * 4 + j;
        float xs = X * sc;
        int x0 = (int)xs; int x1 = x0 + 1; if (x1 > 31) x1 = 31;
        float tx = xs - x0;
        float v00 = r0[x0], v01 = r0[x1];
        float v10 = r1[x0], v11 = r1[x1];
        op[j] = (1.f - ty) * ((1.f - tx) * v00 + tx * v01) + ty * ((1.f - tx) * v10 + tx * v11);
    }
    *reinterpret_cast<float4*>(&out[(size_t)bo * 4096 + Y * 64 + x4 * 4]) = o;
}

// ---------------------------------------------------------------------------
extern "C" void kernel_launch(void* const* d_in, const int* in_sizes, int n_in,
                              void* d_out, int out_size, void* d_ws, size_t ws_size,
                              hipStream_t stream) {
    const float* xa      = (const float*)d_in[0];   // (8,256,64,64)
    const float* xb      = (const float*)d_in[1];
    const float* conv_w  = (const float*)d_in[2];   // (1024,256)
    const float* conv_b  = (const float*)d_in[3];   // (1024,)
    const float* We      = (const float*)d_in[4];   // (1024,1024)
    const float* We2     = (const float*)d_in[5];   // (1024,1024)
    const float* conv2_w = (const float*)d_in[6];   // (256,1024)
    const float* conv2_b = (const float*)d_in[7];   // (256,)
    float* out = (float*)d_out;
    char* ws = (char*)d_ws;

    const long S1M = 1048576;
    const long MiB = 1048576;

    u16*   XT  = (u16*)(ws + 0);
    u16*   T1  = (u16*)(ws + 0);
    u16*   MT  = (u16*)(ws + 0);
    u16*   FA  = (u16*)(ws + 32 * MiB);
    u16*   FB  = (u16*)(ws + 48 * MiB);
    u16*   FAT = (u16*)(ws + 64 * MiB);
    u16*   FBT = (u16*)(ws + 80 * MiB);
    float* V   = (float*)(ws + 64 * MiB);
    u16*   FM  = (u16*)(ws + 96 * MiB);
    u16*   Z   = (u16*)(ws + 96 * MiB);
    u16*   CW  = (u16*)(ws + 128 * MiB);
    u16*   WE  = (u16*)(ws + 128 * MiB + 524288);
    u16*   WE2 = (u16*)(ws + 128 * MiB + 2621440);
    u16*   C2W = (u16*)(ws + 128 * MiB + 4718592);
    float* RIV = (float*)(ws + 128 * MiB + 5242880);   // 16x1024 fp32

    const dim3 tb64(64, 8);

    // 1. weights fp32 -> bf16
    cvt4_k<<<10240, 256, 0, stream>>>(conv_w, CW, We, WE, We2, WE2, conv2_w, C2W);

    // 2. input transpose+convert: XT[z][spatial][ch]
    transpose_in_k<<<dim3(64, 4, 16), tb64, 0, stream>>>(xa, xb, XT);

    // 3. conv1 + bias + 2x2 maxpool -> FA/FB (ch-major) + FAT/FBT (spatial-major)
    gemm2p_pool<<<dim3(8, 32, 16), 256, 0, stream>>>(
        CW, XT, S1M, FA, S1M, FAT, conv_b, 256);

    // 4. T1: path a = FBT . We^T ; path b = FAT . We2^T   (3-buffer BK=32)
    gemm3b_nt<true><<<dim3(8, 8, 16), 256, 0, stream>>>(
        FBT, FAT, S1M, WE, WE2, 0, T1, S1M, 1024, 1024);

    // 5. fm: path a = T1 . FAT^T ; path b = T1 . FBT^T
    gemm3b_nt<true><<<dim3(8, 8, 16), 256, 0, stream>>>(
        T1, T1 + 8 * S1M, S1M, FAT, FBT, S1M, FM, S1M, 1024, 1024);

    // 6. row inverse norms of relu(fm)
    norm_rk<<<16384, 256, 0, stream>>>(FM, RIV);

    // 7. MT[q][p] = relu(fm[p][q]) * rinv[p]
    transpose_scale_k<<<dim3(16, 16, 16), tb64, 0, stream>>>(FM, RIV, MT);

    // 8. en: path a = FA . MT^T ; path b = FB . MT^T  -> Z (ch x spatial)
    gemm3b_nt<true><<<dim3(8, 8, 16), 256, 0, stream>>>(
        FA, FB, S1M, MT, MT + 8 * S1M, S1M, Z, S1M, 1024, 1024);

    // 9. conv2 + bias (fp32 out): triple-buffer BK=32 structure
    gemm3b_c2<<<dim3(2, 8, 16), 256, 0, stream>>>(
        C2W, Z, S1M, V, 256L * 1024, conv2_b, 1024, 1024);

    // 10. bilinear x2 upsample -> d_out (float4 stores)
    upsample4_k<<<16384, 256, 0, stream>>>(V, out, 4194304);
}